// Round 17
// baseline (496.546 us; speedup 1.0000x reference)
//
#include <hip/hip_runtime.h>
#include <hip/hip_bf16.h>
#include <hip/hip_fp16.h>
#include <cstddef>

#define IMW   96
#define HWSZ  (IMW*IMW)       // 9216
#define CTOT  512
#define CHG   256             // channels per group
#define NBATCH 8
#define ROWP  104             // padded LDS row stride (ushorts)
#define XT_LD 280             // mix staging stride (ushorts)
#define TO_LD 76              // mix transpose stride (ushorts)

typedef float    f32x4  __attribute__((ext_vector_type(4)));
typedef _Float16 f16x8  __attribute__((ext_vector_type(8)));
typedef _Float16 f16x2  __attribute__((ext_vector_type(2)));
typedef __fp16   fp16x2b __attribute__((ext_vector_type(2)));   // builtin return type

union U32H2 { unsigned u; f16x2 h; fp16x2b hb; __half2 hh; };

// packed f32x2 -> fp16x2 (v_cvt_pkrtz_f16_f32)
__device__ __forceinline__ unsigned pkh(float lo, float hi) {
    U32H2 v; v.hb = __builtin_amdgcn_cvt_pkrtz(lo, hi); return v.u;
}
__device__ __forceinline__ f16x2 h2(unsigned u) { U32H2 v; v.u = u; return v.h; }
__device__ __forceinline__ unsigned h2u(f16x2 h) { U32H2 v; v.h = h; return v.u; }
__device__ __forceinline__ f16x2 exp2h(f16x2 a) {        // packed f16 exp
    U32H2 v; v.h = a; v.hh = h2exp(v.hh); return v.h;
}
__device__ __forceinline__ f16x2 rcp2h(f16x2 a) {        // packed f16 rcp
    U32H2 v; v.h = a; v.hh = h2rcp(v.hh); return v.h;
}
__device__ __forceinline__ f16x2 bc2(float f) {          // broadcast f32 -> f16x2
    const _Float16 h = (_Float16)f; return (f16x2){h, h};
}

// ---- tiny: convert w_mix (2x256x256 fp32) to fp16 once per launch ----
__global__ __launch_bounds__(256) void wconv_kernel(const float* __restrict__ w,
                                                    unsigned* __restrict__ wh) {
    const int i = blockIdx.x * 256 + threadIdx.x;   // pair index
    wh[i] = pkh(w[2 * i], w[2 * i + 1]);
}

// ---------------- kernel 1: grouped 1x1 conv + shuffle, fp16 MFMA ----------------
// 512 threads (8 waves). Each wave: 64 px x 32 o. XB=0: x fp32; XB=1: x fp16
// (16B staging loads: uint4 of rows k,k+1 -> pack). Epilogue transposes acc
// through LDS for fully-covered 128B-line stores.
template<bool XB>
__global__ __launch_bounds__(512, 4) void mix_mfma(
    const void* __restrict__ xin, const ushort* __restrict__ wh,
    ushort* __restrict__ h)
{
    const int pt = blockIdx.x * 64;
    const int b  = blockIdx.y >> 1, g = blockIdx.y & 1;
    const size_t xoff = ((size_t)b * CTOT + (size_t)g * CHG) * HWSZ;
    const ushort* wg = wh + (size_t)g * CHG * CHG;
    ushort* hb = h + (size_t)b * CTOT * HWSZ;

    __shared__ ushort XtBuf[19456];   // staging [64][280] then transpose [256][76]

    const int t = threadIdx.x;

    if constexpr (XB) {
        // 16B loads: thread covers 8 px x 2 k per iter, 2 iters
        const int px8 = (t & 7) * 8;       // px octet
        const int tk2 = t >> 3;            // k-pair 0..63
        const ushort* xb = (const ushort*)xin + xoff;
        #pragma unroll
        for (int it = 0; it < 2; ++it) {
            const int k = 128 * it + 2 * tk2;
            uint4 a = *(const uint4*)&xb[(size_t)k       * HWSZ + pt + px8];
            uint4 bq = *(const uint4*)&xb[(size_t)(k + 1) * HWSZ + pt + px8];
            const unsigned av[4] = {a.x, a.y, a.z, a.w};
            const unsigned bv[4] = {bq.x, bq.y, bq.z, bq.w};
            #pragma unroll
            for (int j = 0; j < 4; ++j) {
                const unsigned d0 = (av[j] & 0xFFFFu) | (bv[j] << 16);
                const unsigned d1 = (av[j] >> 16) | (bv[j] & 0xFFFF0000u);
                *(unsigned*)&XtBuf[(px8 + 2 * j + 0) * XT_LD + k] = d0;
                *(unsigned*)&XtBuf[(px8 + 2 * j + 1) * XT_LD + k] = d1;
            }
        }
    } else {
        const int tq = t & 15;             // pixel quad
        const int tk = t >> 4;             // k-pair selector 0..31
        const float* xb = (const float*)xin + xoff;
        #pragma unroll
        for (int it = 0; it < 4; ++it) {   // covers all k (4 x 64)
            const int k = 64 * it + 2 * tk;
            float4 a0 = *(const float4*)&xb[(size_t)k       * HWSZ + pt + 4 * tq];
            float4 a1 = *(const float4*)&xb[(size_t)(k + 1) * HWSZ + pt + 4 * tq];
            *(unsigned*)&XtBuf[(4 * tq + 0) * XT_LD + k] = pkh(a0.x, a1.x);
            *(unsigned*)&XtBuf[(4 * tq + 1) * XT_LD + k] = pkh(a0.y, a1.y);
            *(unsigned*)&XtBuf[(4 * tq + 2) * XT_LD + k] = pkh(a0.z, a1.z);
            *(unsigned*)&XtBuf[(4 * tq + 3) * XT_LD + k] = pkh(a0.w, a1.w);
        }
    }
    __syncthreads();

    const int wv  = t >> 6;            // wave 0..7 -> 32 o-channels each
    const int ln  = t & 63;
    const int row = ln & 15;
    const int kb  = ln >> 4;

    f32x4 acc[4][2];
    #pragma unroll
    for (int m = 0; m < 4; ++m)
        #pragma unroll
        for (int n = 0; n < 2; ++n)
            acc[m][n] = (f32x4){0.f, 0.f, 0.f, 0.f};

    #pragma unroll
    for (int ks = 0; ks < 8; ++ks) {
        f16x8 Xf[4], Wf[2];
        #pragma unroll
        for (int m = 0; m < 4; ++m)
            Xf[m] = *(const f16x8*)&XtBuf[(16 * m + row) * XT_LD + 32 * ks + 8 * kb];
        #pragma unroll
        for (int n = 0; n < 2; ++n)
            Wf[n] = *(const f16x8*)&wg[(size_t)(32 * wv + 16 * n + row) * CHG + 32 * ks + 8 * kb];
        #pragma unroll
        for (int m = 0; m < 4; ++m)
            #pragma unroll
            for (int n = 0; n < 2; ++n)
                acc[m][n] = __builtin_amdgcn_mfma_f32_16x16x32_f16(Xf[m], Wf[n], acc[m][n], 0, 0, 0);
    }

    __syncthreads();   // all Xf reads done; reuse buffer for transpose
    #pragma unroll
    for (int m = 0; m < 4; ++m) {
        #pragma unroll
        for (int n = 0; n < 2; ++n) {
            const int o = 32 * wv + 16 * n + row;
            *(uint2*)&XtBuf[o * TO_LD + 16 * m + 4 * kb] =
                make_uint2(pkh(acc[m][n][0], acc[m][n][1]), pkh(acc[m][n][2], acc[m][n][3]));
        }
    }
    __syncthreads();
    const int o8i = t >> 3;            // 0..63
    const int px8s = (t & 7) * 8;      // 0..56
    #pragma unroll
    for (int j = 0; j < 4; ++j) {
        const int o2 = o8i + 64 * j;
        const int c  = 2 * o2 + g;     // channel shuffle folded
        uint4 v = *(const uint4*)&XtBuf[o2 * TO_LD + px8s];
        *(uint4*)&hb[(size_t)c * HWSZ + pt + px8s] = v;
    }
}

// ---- plane part A: dwconv3x3 (packed fp16, own row from regs) + gate + moments ----
__device__ __forceinline__ void plane_partA(
    const ushort* __restrict__ sh, const ushort* __restrict__ sx,
    float* __restrict__ red, int tid, int r, int s6, int x0,
    uint4 hh0, uint4 hh1,
    const float* __restrict__ wc, f16x2 (&cp)[8], unsigned (&ea)[8])
{
    #pragma unroll
    for (int m = 0; m < 8; ++m) cp[m] = (f16x2){(_Float16)0.f, (_Float16)0.f};
    #pragma unroll
    for (int ky = 0; ky < 3; ++ky) {
        const int yy = r + ky - 1;
        if ((unsigned)yy < IMW) {
            const ushort* rp = sh + yy * ROWP + x0;
            unsigned gg[8];
            if (ky == 1) {          // own row: staged regs, no LDS re-read
                gg[0] = hh0.x; gg[1] = hh0.y; gg[2] = hh0.z; gg[3] = hh0.w;
                gg[4] = hh1.x; gg[5] = hh1.y; gg[6] = hh1.z; gg[7] = hh1.w;
            } else {
                uint4 ga4 = *(const uint4*)rp;
                uint4 gb4 = *(const uint4*)(rp + 8);
                gg[0] = ga4.x; gg[1] = ga4.y; gg[2] = ga4.z; gg[3] = ga4.w;
                gg[4] = gb4.x; gg[5] = gb4.y; gg[6] = gb4.z; gg[7] = gb4.w;
            }
            const unsigned L = (s6 > 0) ? *(const unsigned*)(rp - 2)  : 0u;
            const unsigned R = (s6 < 5) ? *(const unsigned*)(rp + 16) : 0u;
            unsigned S[9];
            S[0] = (L >> 16) | (gg[0] << 16);
            #pragma unroll
            for (int m = 1; m < 8; ++m) S[m] = (gg[m - 1] >> 16) | (gg[m] << 16);
            S[8] = (gg[7] >> 16) | (R << 16);
            const _Float16 w0 = (_Float16)wc[3 * ky], w1 = (_Float16)wc[3 * ky + 1],
                           w2 = (_Float16)wc[3 * ky + 2];
            const f16x2 w0_2 = (f16x2){w0, w0}, w1_2 = (f16x2){w1, w1}, w2_2 = (f16x2){w2, w2};
            #pragma unroll
            for (int m = 0; m < 8; ++m)
                cp[m] = cp[m] + w0_2 * h2(S[m]) + w1_2 * h2(gg[m]) + w2_2 * h2(S[m + 1]);
        }
    }
    // gate (packed fp16, roll semantics wrap)
    f16x2 gt2[8];
    #pragma unroll
    for (int m = 0; m < 8; ++m) gt2[m] = (f16x2){(_Float16)0.f, (_Float16)0.f};
    {
        const ushort* xrp = sx + r * ROWP + x0;
        uint4 xa4 = *(const uint4*)xrp;
        uint4 xb4 = *(const uint4*)(xrp + 8);
        unsigned xc[8] = {xa4.x, xa4.y, xa4.z, xa4.w, xb4.x, xb4.y, xb4.z, xb4.w};
        const int lx1 = (x0 == 0) ? (IMW - 2) : (x0 - 2);
        const int lx2 = (x0 == 0) ? (IMW - 4) : (x0 - 4);
        const unsigned L1 = *(const unsigned*)(sx + r * ROWP + lx1);
        const unsigned L2 = *(const unsigned*)(sx + r * ROWP + lx2);
        unsigned p1[8], p2[8], p4[8];
        p1[0] = (L1 >> 16) | (xc[0] << 16);
        #pragma unroll
        for (int m = 1; m < 8; ++m) p1[m] = (xc[m - 1] >> 16) | (xc[m] << 16);
        p2[0] = L1;
        #pragma unroll
        for (int m = 1; m < 8; ++m) p2[m] = xc[m - 1];
        p4[0] = L2; p4[1] = L1;
        #pragma unroll
        for (int m = 2; m < 8; ++m) p4[m] = xc[m - 2];
        #pragma unroll
        for (int m = 0; m < 8; ++m) {
            const f16x2 xcm = h2(xc[m]);
            gt2[m] = gt2[m] + h2(h2u(xcm - h2(p1[m])) & 0x7FFF7FFFu);
            gt2[m] = gt2[m] + h2(h2u(xcm - h2(p2[m])) & 0x7FFF7FFFu);
            gt2[m] = gt2[m] + h2(h2u(xcm - h2(p4[m])) & 0x7FFF7FFFu);
        }
        #pragma unroll
        for (int dd = 0; dd < 3; ++dd) {
            int ym = r - (1 << dd); if (ym < 0) ym += IMW;
            const ushort* vp = sx + ym * ROWP + x0;
            uint4 va = *(const uint4*)vp;
            uint4 vb = *(const uint4*)(vp + 8);
            unsigned vv[8] = {va.x, va.y, va.z, va.w, vb.x, vb.y, vb.z, vb.w};
            #pragma unroll
            for (int m = 0; m < 8; ++m)
                gt2[m] = gt2[m] + h2(h2u(h2(xc[m]) - h2(vv[m])) & 0x7FFF7FFFu);
        }
    }
    // gate exp in packed f16; fills the reduction shadow
    const f16x2 kthird = bc2(-1.f / 3.f);
    #pragma unroll
    for (int m = 0; m < 8; ++m)
        ea[m] = h2u(exp2h(gt2[m] * kthird));
    // instance-norm moment partial sums (f32 accumulate)
    float s = 0.f, s2 = 0.f;
#if __has_builtin(__builtin_amdgcn_fdot2)
    const f16x2 one2d = bc2(1.f);
    #pragma unroll
    for (int m = 0; m < 8; ++m) {
        s  = __builtin_amdgcn_fdot2(cp[m], one2d, s,  false);
        s2 = __builtin_amdgcn_fdot2(cp[m], cp[m], s2, false);
    }
#else
    #pragma unroll
    for (int m = 0; m < 8; ++m) {
        const float c0 = (float)cp[m][0], c1 = (float)cp[m][1];
        s += c0 + c1;
        s2 = fmaf(c0, c0, fmaf(c1, c1, s2));
    }
#endif
    #pragma unroll
    for (int off = 32; off; off >>= 1) {
        s  += __shfl_down(s, off, 64);
        s2 += __shfl_down(s2, off, 64);
    }
    if ((tid & 63) == 0) { red[tid >> 6] = s; red[16 + (tid >> 6)] = s2; }
}

// ---- plane tail: packed-fp16 affine + fused gate*gelu + residual update ----
template<bool EQv, bool OF32v, bool WRXv>
__device__ __forceinline__ void plane_tail(
    const ushort* __restrict__ sx, int r, int x0,
    const f16x2 (&cp)[8], const unsigned (&ea)[8],
    uint4 pva, uint4 pvb,
    float mu, float ga, float be, float alpha,
    size_t gidx, void* __restrict__ out, ushort* __restrict__ xaux)
{
    const ushort* xrp = sx + r * ROWP + x0;
    const uint4 xqa = *(const uint4*)xrp;
    const uint4 xqb = *(const uint4*)(xrp + 8);
    const unsigned xu[8] = {xqa.x, xqa.y, xqa.z, xqa.w, xqb.x, xqb.y, xqb.z, xqb.w};
    unsigned pu[8];
    if constexpr (!EQv) {
        pu[0] = pva.x; pu[1] = pva.y; pu[2] = pva.z; pu[3] = pva.w;
        pu[4] = pvb.x; pu[5] = pvb.y; pu[6] = pvb.z; pu[7] = pvb.w;
    }
    const f16x2 mu2 = bc2(mu), ga2 = bc2(ga), be2 = bc2(be), al2 = bc2(alpha);
    const f16x2 one2 = bc2(1.f);
    const f16x2 k1_2 = bc2(0.044715f);
    const f16x2 mk2  = bc2(-1.5957691216f);
    f16x2 o2[8];
    #pragma unroll
    for (int m = 0; m < 8; ++m) {
        const f16x2 x2 = h2(xu[m]);
        const f16x2 hn = (cp[m] - mu2) * ga2 + be2;
        const f16x2 w  = hn * hn;
        const f16x2 tt = k1_2 * w + one2;          // 1 + 0.044715 hn^2
        const f16x2 z2n = (hn * tt) * mk2;         // -1.59577 * (hn + 0.044715 hn^3)
        const f16x2 eb = exp2h(z2n);
        const f16x2 eaa = h2(ea[m]);
        const f16x2 den = (one2 + eaa) * (one2 + eb);
        const f16x2 gg = hn * rcp2h(den);          // gate * gelu
        if constexpr (EQv) {
            o2[m] = x2 + gg;
        } else {
            const f16x2 pvv = h2(pu[m]);
            o2[m] = al2 * (x2 - pvv) + (x2 + gg);
        }
    }
    if constexpr (OF32v) {
        float o[16];
        #pragma unroll
        for (int m = 0; m < 8; ++m) { o[2 * m] = (float)o2[m][0]; o[2 * m + 1] = (float)o2[m][1]; }
        float* op = (float*)out + gidx;
        *(float4*)(op)      = make_float4(o[0],  o[1],  o[2],  o[3]);
        *(float4*)(op + 4)  = make_float4(o[4],  o[5],  o[6],  o[7]);
        *(float4*)(op + 8)  = make_float4(o[8],  o[9],  o[10], o[11]);
        *(float4*)(op + 12) = make_float4(o[12], o[13], o[14], o[15]);
    } else {
        ushort* op = (ushort*)out + gidx;
        *(uint4*)op       = make_uint4(h2u(o2[0]), h2u(o2[1]), h2u(o2[2]), h2u(o2[3]));
        *(uint4*)(op + 8) = make_uint4(h2u(o2[4]), h2u(o2[5]), h2u(o2[6]), h2u(o2[7]));
    }
    if constexpr (WRXv) {
        ushort* xp = xaux + gidx;
        *(uint4*)xp = xqa; *(uint4*)(xp + 8) = xqb;
    }
}

// ------- kernel 2: single-plane fused dwconv3x3+IN+GELU+gate+update -------
// 4096 blocks, max TLP. prev ALWAYS fp16. Alias (t2: out==prev buffer): pv
// read is own px, store value depends on it -> same-thread read-before-write.
template<bool XF32, bool EQ, bool OF32, bool WRX>
__global__ __launch_bounds__(576, 4) void plane1_kernel(
    const ushort* __restrict__ hmid,
    const void* __restrict__ xcur, const ushort* __restrict__ xprev,
    const float* __restrict__ wdw,
    const float* __restrict__ gammas, const float* __restrict__ betas,
    const float* __restrict__ alphap, int t,
    void* __restrict__ out, ushort* __restrict__ xaux)
{
    __shared__ ushort sh[IMW * ROWP];   // h plane fp16 (~20 KB)
    __shared__ ushort sx[IMW * ROWP];   // x plane fp16 (~20 KB)
    __shared__ float  red[32];

    const int tid = threadIdx.x;
    const int r   = tid / 6;
    const int s6  = tid - r * 6;
    const int x0  = s6 * 16;
    const int pix = r * IMW + x0;
    const size_t off = (size_t)blockIdx.x * HWSZ;
    const int c = blockIdx.x & (CTOT - 1);

    const float gam   = gammas[t * CTOT + c];
    const float be    = betas[t * CTOT + c];
    const float alpha = alphap[0];
    const float* wc   = wdw + c * 9;

    // ---- pre-barrier: own-x load, pv load, h stage (regs kept), sx stage ----
    uint4 h0, h1;
    uint4 pa, pb;
    {
        uint4 xa, xb;
        if constexpr (XF32) {
            const float4* s = (const float4*)((const float*)xcur + off + pix);
            float4 v0 = s[0], v1 = s[1], v2 = s[2], v3 = s[3];
            xa = make_uint4(pkh(v0.x, v0.y), pkh(v0.z, v0.w), pkh(v1.x, v1.y), pkh(v1.z, v1.w));
            xb = make_uint4(pkh(v2.x, v2.y), pkh(v2.z, v2.w), pkh(v3.x, v3.y), pkh(v3.z, v3.w));
        } else {
            const uint4* s = (const uint4*)((const ushort*)xcur + off + pix);
            xa = s[0]; xb = s[1];
        }
        if constexpr (!EQ) {
            const uint4* s = (const uint4*)(xprev + off + pix);
            pa = s[0]; pb = s[1];
        }
        const uint4* hs = (const uint4*)(hmid + off + (size_t)r * IMW);
        h0 = hs[2 * s6]; h1 = hs[2 * s6 + 1];
        uint4* hd = (uint4*)(sh + r * ROWP);
        hd[2 * s6] = h0; hd[2 * s6 + 1] = h1;
        uint4* xd = (uint4*)(sx + r * ROWP + x0);
        xd[0] = xa; xd[1] = xb;
    }
    __syncthreads();   // B1: LDS staged

    f16x2 cp[8]; unsigned ea[8];
    plane_partA(sh, sx, red, tid, r, s6, x0, h0, h1, wc, cp, ea);
    __syncthreads();   // B2: moments ready
    float mu, ga;
    {
        float ssum = 0.f, s2sum = 0.f;
        #pragma unroll
        for (int q = 0; q < 9; ++q) { ssum += red[q]; s2sum += red[16 + q]; }
        mu = ssum * (1.f / HWSZ);
        const float var = fmaxf(s2sum * (1.f / HWSZ) - mu * mu, 0.f);
        ga = gam * rsqrtf(var + 1e-5f);
    }
    plane_tail<EQ, OF32, WRX>(sx, r, x0, cp, ea, pa, pb, mu, ga, be, alpha,
                              off + pix, out, xaux);
}

extern "C" void kernel_launch(void* const* d_in, const int* in_sizes, int n_in,
                              void* d_out, int out_size, void* d_ws, size_t ws_size,
                              hipStream_t stream) {
    const float* x0     = (const float*)d_in[0];
    const float* wmix   = (const float*)d_in[1];
    const float* wdw    = (const float*)d_in[2];
    const float* gammas = (const float*)d_in[3];
    const float* betas  = (const float*)d_in[4];
    const float* alphap = (const float*)d_in[5];

    const size_t NELEM = (size_t)NBATCH * CTOT * HWSZ;   // 37,748,736
    float*  D   = (float*)d_out;                          // final x4 (fp32)
    ushort* X0h = (ushort*)d_out;                         // scratch: fp16 copy of x0 (t0->t1 only)
    char*   ws  = (char*)d_ws;
    ushort* X1h = (ushort*)ws;                            // x1, then x3 (fp16)
    ushort* X2h = (ushort*)(ws + NELEM * 2);              // x2 (fp16)
    ushort* Hb  = (ushort*)(ws + NELEM * 4);              // mix output (fp16)
    ushort* Wh  = (ushort*)(ws + NELEM * 6);              // w_mix fp16 (256 KB)

    wconv_kernel<<<256, 256, 0, stream>>>(wmix, (unsigned*)Wh);

    dim3 mgrid(HWSZ / 64, NBATCH * 2);   // (144, 16)
    const int pgrid = NBATCH * CTOT;     // 4096

    // t=0: cur=prev=x0 (fp32) -> X1h; also write fp16 copy of x0 into X0h
    mix_mfma<false><<<mgrid, 512, 0, stream>>>(x0, Wh, Hb);
    plane1_kernel<true, true, false, true><<<pgrid, 576, 0, stream>>>(
        Hb, x0, nullptr, wdw, gammas, betas, alphap, 0, X1h, X0h);
    // t=1: cur=X1h prev=X0h -> X2h
    mix_mfma<true><<<mgrid, 512, 0, stream>>>(X1h, Wh, Hb);
    plane1_kernel<false, false, false, false><<<pgrid, 576, 0, stream>>>(
        Hb, X1h, X0h, wdw, gammas, betas, alphap, 1, X2h, nullptr);
    // t=2: cur=X2h prev=X1h -> X1h (same-thread read-before-write alias)
    mix_mfma<true><<<mgrid, 512, 0, stream>>>(X2h, Wh, Hb);
    plane1_kernel<false, false, false, false><<<pgrid, 576, 0, stream>>>(
        Hb, X2h, X1h, wdw, gammas, betas, alphap, 2, X1h, nullptr);
    // t=3: cur=X1h(x3) prev=X2h -> D (fp32 final; overwrites X0h scratch, safe)
    mix_mfma<true><<<mgrid, 512, 0, stream>>>(X1h, Wh, Hb);
    plane1_kernel<false, false, true, false><<<pgrid, 576, 0, stream>>>(
        Hb, X1h, X2h, wdw, gammas, betas, alphap, 3, D, nullptr);
}

// Round 18
// 489.908 us; speedup vs baseline: 1.0135x; 1.0135x over previous
//
#include <hip/hip_runtime.h>
#include <hip/hip_bf16.h>
#include <hip/hip_fp16.h>
#include <cstddef>

#define IMW   96
#define HWSZ  (IMW*IMW)       // 9216
#define CTOT  512
#define CHG   256             // channels per group
#define NBATCH 8
#define ROWP  104             // padded LDS row stride (ushorts)
#define XT_LD 280             // mix staging stride (ushorts)
#define TO_LD 76              // mix transpose stride (ushorts)

typedef float    f32x4  __attribute__((ext_vector_type(4)));
typedef _Float16 f16x8  __attribute__((ext_vector_type(8)));
typedef _Float16 f16x2  __attribute__((ext_vector_type(2)));
typedef __fp16   fp16x2b __attribute__((ext_vector_type(2)));   // builtin return type

union U32H2 { unsigned u; f16x2 h; fp16x2b hb; __half2 hh; };

// packed f32x2 -> fp16x2 (v_cvt_pkrtz_f16_f32)
__device__ __forceinline__ unsigned pkh(float lo, float hi) {
    U32H2 v; v.hb = __builtin_amdgcn_cvt_pkrtz(lo, hi); return v.u;
}
__device__ __forceinline__ f16x2 h2(unsigned u) { U32H2 v; v.u = u; return v.h; }
__device__ __forceinline__ unsigned h2u(f16x2 h) { U32H2 v; v.h = h; return v.u; }
__device__ __forceinline__ f16x2 exp2h(f16x2 a) {        // packed f16 exp
    U32H2 v; v.h = a; v.hh = h2exp(v.hh); return v.h;
}
__device__ __forceinline__ f16x2 rcp2h(f16x2 a) {        // packed f16 rcp
    U32H2 v; v.h = a; v.hh = h2rcp(v.hh); return v.h;
}
__device__ __forceinline__ f16x2 bc2(float f) {          // broadcast f32 -> f16x2
    const _Float16 h = (_Float16)f; return (f16x2){h, h};
}

// ---- tiny: convert w_mix (2x256x256 fp32) to fp16 once per launch ----
__global__ __launch_bounds__(256) void wconv_kernel(const float* __restrict__ w,
                                                    unsigned* __restrict__ wh) {
    const int i = blockIdx.x * 256 + threadIdx.x;   // pair index
    wh[i] = pkh(w[2 * i], w[2 * i + 1]);
}

// ---------------- kernel 1: grouped 1x1 conv + shuffle, fp16 MFMA ----------------
// 512 threads (8 waves). Each wave: 64 px x 32 o. XB=0: x fp32; XB=1: x fp16.
// Epilogue transposes acc through LDS for fully-covered 128B-line stores.
template<bool XB>
__global__ __launch_bounds__(512, 4) void mix_mfma(
    const void* __restrict__ xin, const ushort* __restrict__ wh,
    ushort* __restrict__ h)
{
    const int pt = blockIdx.x * 64;
    const int b  = blockIdx.y >> 1, g = blockIdx.y & 1;
    const size_t xoff = ((size_t)b * CTOT + (size_t)g * CHG) * HWSZ;
    const ushort* wg = wh + (size_t)g * CHG * CHG;
    ushort* hb = h + (size_t)b * CTOT * HWSZ;

    __shared__ ushort XtBuf[19456];   // staging [64][280] then transpose [256][76]

    const int t  = threadIdx.x;
    const int tq = t & 15;             // pixel quad
    const int tk = t >> 4;             // k-pair selector 0..31

    #pragma unroll
    for (int it = 0; it < 4; ++it) {   // covers all k (4 x 64)
        const int k = 64 * it + 2 * tk;
        unsigned u0, u1, u2, u3;
        if constexpr (XB) {
            const ushort* xb = (const ushort*)xin + xoff;
            ushort4 a0 = *(const ushort4*)&xb[(size_t)k       * HWSZ + pt + 4 * tq];
            ushort4 a1 = *(const ushort4*)&xb[(size_t)(k + 1) * HWSZ + pt + 4 * tq];
            u0 = (unsigned)a0.x | ((unsigned)a1.x << 16);
            u1 = (unsigned)a0.y | ((unsigned)a1.y << 16);
            u2 = (unsigned)a0.z | ((unsigned)a1.z << 16);
            u3 = (unsigned)a0.w | ((unsigned)a1.w << 16);
        } else {
            const float* xb = (const float*)xin + xoff;
            float4 a0 = *(const float4*)&xb[(size_t)k       * HWSZ + pt + 4 * tq];
            float4 a1 = *(const float4*)&xb[(size_t)(k + 1) * HWSZ + pt + 4 * tq];
            u0 = pkh(a0.x, a1.x);
            u1 = pkh(a0.y, a1.y);
            u2 = pkh(a0.z, a1.z);
            u3 = pkh(a0.w, a1.w);
        }
        *(unsigned*)&XtBuf[(4 * tq + 0) * XT_LD + k] = u0;
        *(unsigned*)&XtBuf[(4 * tq + 1) * XT_LD + k] = u1;
        *(unsigned*)&XtBuf[(4 * tq + 2) * XT_LD + k] = u2;
        *(unsigned*)&XtBuf[(4 * tq + 3) * XT_LD + k] = u3;
    }
    __syncthreads();

    const int wv  = t >> 6;            // wave 0..7 -> 32 o-channels each
    const int ln  = t & 63;
    const int row = ln & 15;
    const int kb  = ln >> 4;

    f32x4 acc[4][2];
    #pragma unroll
    for (int m = 0; m < 4; ++m)
        #pragma unroll
        for (int n = 0; n < 2; ++n)
            acc[m][n] = (f32x4){0.f, 0.f, 0.f, 0.f};

    #pragma unroll
    for (int ks = 0; ks < 8; ++ks) {
        f16x8 Xf[4], Wf[2];
        #pragma unroll
        for (int m = 0; m < 4; ++m)
            Xf[m] = *(const f16x8*)&XtBuf[(16 * m + row) * XT_LD + 32 * ks + 8 * kb];
        #pragma unroll
        for (int n = 0; n < 2; ++n)
            Wf[n] = *(const f16x8*)&wg[(size_t)(32 * wv + 16 * n + row) * CHG + 32 * ks + 8 * kb];
        #pragma unroll
        for (int m = 0; m < 4; ++m)
            #pragma unroll
            for (int n = 0; n < 2; ++n)
                acc[m][n] = __builtin_amdgcn_mfma_f32_16x16x32_f16(Xf[m], Wf[n], acc[m][n], 0, 0, 0);
    }

    __syncthreads();   // all Xf reads done; reuse buffer for transpose
    #pragma unroll
    for (int m = 0; m < 4; ++m) {
        #pragma unroll
        for (int n = 0; n < 2; ++n) {
            const int o = 32 * wv + 16 * n + row;
            *(uint2*)&XtBuf[o * TO_LD + 16 * m + 4 * kb] =
                make_uint2(pkh(acc[m][n][0], acc[m][n][1]), pkh(acc[m][n][2], acc[m][n][3]));
        }
    }
    __syncthreads();
    const int o8i = t >> 3;            // 0..63
    const int px8 = (t & 7) * 8;       // 0..56
    #pragma unroll
    for (int j = 0; j < 4; ++j) {
        const int o2 = o8i + 64 * j;
        const int c  = 2 * o2 + g;     // channel shuffle folded
        uint4 v = *(const uint4*)&XtBuf[o2 * TO_LD + px8];
        *(uint4*)&hb[(size_t)c * HWSZ + pt + px8] = v;
    }
}

// ---- plane part A: dwconv3x3 (packed fp16) + gate exp (packed f16) + moments ----
__device__ __forceinline__ void plane_partA(
    const ushort* __restrict__ sh, const ushort* __restrict__ sx,
    float* __restrict__ red, int tid, int r, int s6, int x0,
    const float* __restrict__ wc, f16x2 (&cp)[8], unsigned (&ea)[8])
{
    #pragma unroll
    for (int m = 0; m < 8; ++m) cp[m] = (f16x2){(_Float16)0.f, (_Float16)0.f};
    #pragma unroll
    for (int ky = 0; ky < 3; ++ky) {
        const int yy = r + ky - 1;
        if ((unsigned)yy < IMW) {
            const ushort* rp = sh + yy * ROWP + x0;
            uint4 ga4 = *(const uint4*)rp;
            uint4 gb4 = *(const uint4*)(rp + 8);
            unsigned gg[8] = {ga4.x, ga4.y, ga4.z, ga4.w, gb4.x, gb4.y, gb4.z, gb4.w};
            const unsigned L = (s6 > 0) ? *(const unsigned*)(rp - 2)  : 0u;
            const unsigned R = (s6 < 5) ? *(const unsigned*)(rp + 16) : 0u;
            unsigned S[9];
            S[0] = (L >> 16) | (gg[0] << 16);
            #pragma unroll
            for (int m = 1; m < 8; ++m) S[m] = (gg[m - 1] >> 16) | (gg[m] << 16);
            S[8] = (gg[7] >> 16) | (R << 16);
            const _Float16 w0 = (_Float16)wc[3 * ky], w1 = (_Float16)wc[3 * ky + 1],
                           w2 = (_Float16)wc[3 * ky + 2];
            const f16x2 w0_2 = (f16x2){w0, w0}, w1_2 = (f16x2){w1, w1}, w2_2 = (f16x2){w2, w2};
            #pragma unroll
            for (int m = 0; m < 8; ++m)
                cp[m] = cp[m] + w0_2 * h2(S[m]) + w1_2 * h2(gg[m]) + w2_2 * h2(S[m + 1]);
        }
    }
    // gate (packed fp16, roll semantics wrap)
    f16x2 gt2[8];
    #pragma unroll
    for (int m = 0; m < 8; ++m) gt2[m] = (f16x2){(_Float16)0.f, (_Float16)0.f};
    {
        const ushort* xrp = sx + r * ROWP + x0;
        uint4 xa4 = *(const uint4*)xrp;
        uint4 xb4 = *(const uint4*)(xrp + 8);
        unsigned xc[8] = {xa4.x, xa4.y, xa4.z, xa4.w, xb4.x, xb4.y, xb4.z, xb4.w};
        const int lx1 = (x0 == 0) ? (IMW - 2) : (x0 - 2);
        const int lx2 = (x0 == 0) ? (IMW - 4) : (x0 - 4);
        const unsigned L1 = *(const unsigned*)(sx + r * ROWP + lx1);
        const unsigned L2 = *(const unsigned*)(sx + r * ROWP + lx2);
        unsigned p1[8], p2[8], p4[8];
        p1[0] = (L1 >> 16) | (xc[0] << 16);
        #pragma unroll
        for (int m = 1; m < 8; ++m) p1[m] = (xc[m - 1] >> 16) | (xc[m] << 16);
        p2[0] = L1;
        #pragma unroll
        for (int m = 1; m < 8; ++m) p2[m] = xc[m - 1];
        p4[0] = L2; p4[1] = L1;
        #pragma unroll
        for (int m = 2; m < 8; ++m) p4[m] = xc[m - 2];
        #pragma unroll
        for (int m = 0; m < 8; ++m) {
            const f16x2 xcm = h2(xc[m]);
            gt2[m] = gt2[m] + h2(h2u(xcm - h2(p1[m])) & 0x7FFF7FFFu);
            gt2[m] = gt2[m] + h2(h2u(xcm - h2(p2[m])) & 0x7FFF7FFFu);
            gt2[m] = gt2[m] + h2(h2u(xcm - h2(p4[m])) & 0x7FFF7FFFu);
        }
        #pragma unroll
        for (int dd = 0; dd < 3; ++dd) {
            int ym = r - (1 << dd); if (ym < 0) ym += IMW;
            const ushort* vp = sx + ym * ROWP + x0;
            uint4 va = *(const uint4*)vp;
            uint4 vb = *(const uint4*)(vp + 8);
            unsigned vv[8] = {va.x, va.y, va.z, va.w, vb.x, vb.y, vb.z, vb.w};
            #pragma unroll
            for (int m = 0; m < 8; ++m)
                gt2[m] = gt2[m] + h2(h2u(h2(xc[m]) - h2(vv[m])) & 0x7FFF7FFFu);
        }
    }
    // gate exp in packed f16 (no f32 round-trip); fills the reduction shadow
    const f16x2 kthird = bc2(-1.f / 3.f);
    #pragma unroll
    for (int m = 0; m < 8; ++m)
        ea[m] = h2u(exp2h(gt2[m] * kthird));
    // instance-norm moment partial sums (f32 accumulate)
    float s = 0.f, s2 = 0.f;
#if __has_builtin(__builtin_amdgcn_fdot2)
    const f16x2 one2d = bc2(1.f);
    #pragma unroll
    for (int m = 0; m < 8; ++m) {
        s  = __builtin_amdgcn_fdot2(cp[m], one2d, s,  false);
        s2 = __builtin_amdgcn_fdot2(cp[m], cp[m], s2, false);
    }
#else
    #pragma unroll
    for (int m = 0; m < 8; ++m) {
        const float c0 = (float)cp[m][0], c1 = (float)cp[m][1];
        s += c0 + c1;
        s2 = fmaf(c0, c0, fmaf(c1, c1, s2));
    }
#endif
    #pragma unroll
    for (int off = 32; off; off >>= 1) {
        s  += __shfl_down(s, off, 64);
        s2 += __shfl_down(s2, off, 64);
    }
    if ((tid & 63) == 0) { red[tid >> 6] = s; red[16 + (tid >> 6)] = s2; }
}

// ---- plane tail: packed-fp16 affine + fused gate*gelu + residual update ----
// All v_pk_* / f16 transcendentals. Overflow-safe: hn<0 -> exp(+z2)->inf ->
// rcp->0 -> gg->0 (correct GELU limit).
template<bool EQv, bool OF32v, bool WRXv>
__device__ __forceinline__ void plane_tail(
    const ushort* __restrict__ sx, int r, int x0,
    const f16x2 (&cp)[8], const unsigned (&ea)[8],
    uint4 pva, uint4 pvb,
    float mu, float ga, float be, float alpha,
    size_t gidx, void* __restrict__ out, ushort* __restrict__ xaux)
{
    const ushort* xrp = sx + r * ROWP + x0;
    const uint4 xqa = *(const uint4*)xrp;
    const uint4 xqb = *(const uint4*)(xrp + 8);
    const unsigned xu[8] = {xqa.x, xqa.y, xqa.z, xqa.w, xqb.x, xqb.y, xqb.z, xqb.w};
    unsigned pu[8];
    if constexpr (!EQv) {
        pu[0] = pva.x; pu[1] = pva.y; pu[2] = pva.z; pu[3] = pva.w;
        pu[4] = pvb.x; pu[5] = pvb.y; pu[6] = pvb.z; pu[7] = pvb.w;
    }
    const f16x2 mu2 = bc2(mu), ga2 = bc2(ga), be2 = bc2(be), al2 = bc2(alpha);
    const f16x2 one2 = bc2(1.f);
    const f16x2 k1_2 = bc2(0.044715f);
    const f16x2 mk2  = bc2(-1.5957691216f);
    f16x2 o2[8];
    #pragma unroll
    for (int m = 0; m < 8; ++m) {
        const f16x2 x2 = h2(xu[m]);
        const f16x2 hn = (cp[m] - mu2) * ga2 + be2;
        const f16x2 w  = hn * hn;
        const f16x2 tt = k1_2 * w + one2;          // 1 + 0.044715 hn^2
        const f16x2 z2n = (hn * tt) * mk2;         // -1.59577 * (hn + 0.044715 hn^3)
        const f16x2 eb = exp2h(z2n);
        const f16x2 eaa = h2(ea[m]);
        const f16x2 den = (one2 + eaa) * (one2 + eb);
        const f16x2 gg = hn * rcp2h(den);          // gate * gelu
        if constexpr (EQv) {
            o2[m] = x2 + gg;
        } else {
            const f16x2 pvv = h2(pu[m]);
            o2[m] = al2 * (x2 - pvv) + (x2 + gg);
        }
    }
    if constexpr (OF32v) {
        float o[16];
        #pragma unroll
        for (int m = 0; m < 8; ++m) { o[2 * m] = (float)o2[m][0]; o[2 * m + 1] = (float)o2[m][1]; }
        float* op = (float*)out + gidx;
        *(float4*)(op)      = make_float4(o[0],  o[1],  o[2],  o[3]);
        *(float4*)(op + 4)  = make_float4(o[4],  o[5],  o[6],  o[7]);
        *(float4*)(op + 8)  = make_float4(o[8],  o[9],  o[10], o[11]);
        *(float4*)(op + 12) = make_float4(o[12], o[13], o[14], o[15]);
    } else {
        ushort* op = (ushort*)out + gidx;
        *(uint4*)op       = make_uint4(h2u(o2[0]), h2u(o2[1]), h2u(o2[2]), h2u(o2[3]));
        *(uint4*)(op + 8) = make_uint4(h2u(o2[4]), h2u(o2[5]), h2u(o2[6]), h2u(o2[7]));
    }
    if constexpr (WRXv) {
        ushort* xp = xaux + gidx;
        *(uint4*)xp = xqa; *(uint4*)(xp + 8) = xqb;
    }
}

// ------- kernel 2: single-plane fused dwconv3x3+IN+GELU+gate+update -------
// 4096 blocks, max TLP (576 thr / 9 waves x 3 blocks = 27/32 wave slots).
// prev is ALWAYS fp16. Alias (t2: out==prev buffer): pv read is own px, store
// value depends on it -> same-thread read-before-write.
template<bool XF32, bool EQ, bool OF32, bool WRX>
__global__ __launch_bounds__(576, 4) void plane1_kernel(
    const ushort* __restrict__ hmid,
    const void* __restrict__ xcur, const ushort* __restrict__ xprev,
    const float* __restrict__ wdw,
    const float* __restrict__ gammas, const float* __restrict__ betas,
    const float* __restrict__ alphap, int t,
    void* __restrict__ out, ushort* __restrict__ xaux)
{
    __shared__ ushort sh[IMW * ROWP];   // h plane fp16 (~20 KB)
    __shared__ ushort sx[IMW * ROWP];   // x plane fp16 (~20 KB)
    __shared__ float  red[32];

    const int tid = threadIdx.x;
    const int r   = tid / 6;
    const int s6  = tid - r * 6;
    const int x0  = s6 * 16;
    const int pix = r * IMW + x0;
    const size_t off = (size_t)blockIdx.x * HWSZ;
    const int c = blockIdx.x & (CTOT - 1);

    const float gam   = gammas[t * CTOT + c];
    const float be    = betas[t * CTOT + c];
    const float alpha = alphap[0];
    const float* wc   = wdw + c * 9;

    // ---- pre-barrier: own-x load, h stage, sx stage ----
    {
        uint4 xa, xb;
        if constexpr (XF32) {
            const float4* s = (const float4*)((const float*)xcur + off + pix);
            float4 v0 = s[0], v1 = s[1], v2 = s[2], v3 = s[3];
            xa = make_uint4(pkh(v0.x, v0.y), pkh(v0.z, v0.w), pkh(v1.x, v1.y), pkh(v1.z, v1.w));
            xb = make_uint4(pkh(v2.x, v2.y), pkh(v2.z, v2.w), pkh(v3.x, v3.y), pkh(v3.z, v3.w));
        } else {
            const uint4* s = (const uint4*)((const ushort*)xcur + off + pix);
            xa = s[0]; xb = s[1];
        }
        const uint4* hs = (const uint4*)(hmid + off + (size_t)r * IMW);
        uint4 h0 = hs[2 * s6], h1 = hs[2 * s6 + 1];
        uint4* hd = (uint4*)(sh + r * ROWP);
        hd[2 * s6] = h0; hd[2 * s6 + 1] = h1;
        uint4* xd = (uint4*)(sx + r * ROWP + x0);
        xd[0] = xa; xd[1] = xb;
    }
    __syncthreads();   // B1: LDS staged

    // pv loads issued now; they fly under partA's LDS work
    uint4 pa, pb;
    if constexpr (!EQ) {
        const uint4* s = (const uint4*)(xprev + off + pix);
        pa = s[0]; pb = s[1];
    }

    f16x2 cp[8]; unsigned ea[8];
    plane_partA(sh, sx, red, tid, r, s6, x0, wc, cp, ea);
    __syncthreads();   // B2: moments ready
    float mu, ga;
    {
        float ssum = 0.f, s2sum = 0.f;
        #pragma unroll
        for (int q = 0; q < 9; ++q) { ssum += red[q]; s2sum += red[16 + q]; }
        mu = ssum * (1.f / HWSZ);
        const float var = fmaxf(s2sum * (1.f / HWSZ) - mu * mu, 0.f);
        ga = gam * rsqrtf(var + 1e-5f);
    }
    plane_tail<EQ, OF32, WRX>(sx, r, x0, cp, ea, pa, pb, mu, ga, be, alpha,
                              off + pix, out, xaux);
}

extern "C" void kernel_launch(void* const* d_in, const int* in_sizes, int n_in,
                              void* d_out, int out_size, void* d_ws, size_t ws_size,
                              hipStream_t stream) {
    const float* x0     = (const float*)d_in[0];
    const float* wmix   = (const float*)d_in[1];
    const float* wdw    = (const float*)d_in[2];
    const float* gammas = (const float*)d_in[3];
    const float* betas  = (const float*)d_in[4];
    const float* alphap = (const float*)d_in[5];

    const size_t NELEM = (size_t)NBATCH * CTOT * HWSZ;   // 37,748,736
    float*  D   = (float*)d_out;                          // final x4 (fp32)
    ushort* X0h = (ushort*)d_out;                         // scratch: fp16 copy of x0 (t0->t1 only)
    char*   ws  = (char*)d_ws;
    ushort* X1h = (ushort*)ws;                            // x1, then x3 (fp16)
    ushort* X2h = (ushort*)(ws + NELEM * 2);              // x2 (fp16)
    ushort* Hb  = (ushort*)(ws + NELEM * 4);              // mix output (fp16)
    ushort* Wh  = (ushort*)(ws + NELEM * 6);              // w_mix fp16 (256 KB)

    wconv_kernel<<<256, 256, 0, stream>>>(wmix, (unsigned*)Wh);

    dim3 mgrid(HWSZ / 64, NBATCH * 2);   // (144, 16)
    const int pgrid = NBATCH * CTOT;     // 4096

    // t=0: cur=prev=x0 (fp32) -> X1h; also write fp16 copy of x0 into X0h
    mix_mfma<false><<<mgrid, 512, 0, stream>>>(x0, Wh, Hb);
    plane1_kernel<true, true, false, true><<<pgrid, 576, 0, stream>>>(
        Hb, x0, nullptr, wdw, gammas, betas, alphap, 0, X1h, X0h);
    // t=1: cur=X1h prev=X0h -> X2h
    mix_mfma<true><<<mgrid, 512, 0, stream>>>(X1h, Wh, Hb);
    plane1_kernel<false, false, false, false><<<pgrid, 576, 0, stream>>>(
        Hb, X1h, X0h, wdw, gammas, betas, alphap, 1, X2h, nullptr);
    // t=2: cur=X2h prev=X1h -> X1h (same-thread read-before-write alias)
    mix_mfma<true><<<mgrid, 512, 0, stream>>>(X2h, Wh, Hb);
    plane1_kernel<false, false, false, false><<<pgrid, 576, 0, stream>>>(
        Hb, X2h, X1h, wdw, gammas, betas, alphap, 2, X1h, nullptr);
    // t=3: cur=X1h(x3) prev=X2h -> D (fp32 final; overwrites X0h scratch, safe)
    mix_mfma<true><<<mgrid, 512, 0, stream>>>(X1h, Wh, Hb);
    plane1_kernel<false, false, true, false><<<pgrid, 576, 0, stream>>>(
        Hb, X1h, X2h, wdw, gammas, betas, alphap, 3, D, nullptr);
}